// Round 8
// baseline (603.489 us; speedup 1.0000x reference)
//
#include <hip/hip_runtime.h>
#include <math.h>

#define NV 50000
#define ETR 800000
#define EPOS 200000
#define ETEST 400000

typedef __attribute__((ext_vector_type(8))) short bf16x8;
typedef __attribute__((ext_vector_type(8))) unsigned short ushortx8;
typedef __attribute__((ext_vector_type(4))) float f32x4;

__device__ inline unsigned short f2b(float f) {
    union { float f; unsigned u; } v; v.f = f;
    unsigned r = v.u + 0x7fffu + ((v.u >> 16) & 1u);   // RNE
    return (unsigned short)(r >> 16);
}
__device__ inline float blo(unsigned q) { union { unsigned u; float f; } v; v.u = q << 16; return v.f; }
__device__ inline float bhi(unsigned q) { union { unsigned u; float f; } v; v.u = q & 0xffff0000u; return v.f; }
__device__ inline float b2f(unsigned short s) { union { unsigned u; float f; } v; v.u = ((unsigned)s) << 16; return v.f; }

__device__ inline ushortx8 bf16add8(ushortx8 a, ushortx8 b) {
    ushortx8 r;
    #pragma unroll
    for (int i = 0; i < 8; ++i)
        r[i] = f2b(b2f(a[i]) + b2f(b[i]));
    return r;
}

// ---------------- CSR build ----------------

__global__ void deg_kernel(const int* __restrict__ tei, int* __restrict__ deg) {
    int e = blockIdx.x * blockDim.x + threadIdx.x;
    if (e < ETR) atomicAdd(&deg[tei[ETR + e]], 1);
}

__global__ __launch_bounds__(1024) void partial_kernel(const int* __restrict__ deg,
                                                       int* __restrict__ partials) {
    int i = blockIdx.x * 1024 + threadIdx.x;
    int v = (i < NV) ? deg[i] : 0;
    #pragma unroll
    for (int off = 32; off > 0; off >>= 1) v += __shfl_xor(v, off);
    __shared__ int wsum[16];
    if ((threadIdx.x & 63) == 0) wsum[threadIdx.x >> 6] = v;
    __syncthreads();
    if (threadIdx.x == 0) {
        int s = 0;
        #pragma unroll
        for (int k = 0; k < 16; ++k) s += wsum[k];
        partials[blockIdx.x] = s;
    }
}

__global__ __launch_bounds__(1024) void ptr_kernel(
    const int* __restrict__ deg, const int* __restrict__ partials,
    int* __restrict__ ptr, int* __restrict__ cursor, float* __restrict__ dinv)
{
    int b = blockIdx.x, t = threadIdx.x;
    int i = b * 1024 + t;
    int d = (i < NV) ? deg[i] : 0;
    int lane = t & 63, w = t >> 6;
    int v = d;
    #pragma unroll
    for (int off = 1; off < 64; off <<= 1) {
        int u = __shfl_up(v, off);
        if (lane >= off) v += u;
    }
    __shared__ int wsum[16], woff[16];
    if (lane == 63) wsum[w] = v;
    __syncthreads();
    if (t == 0) {
        int s = 0;
        for (int k = 0; k < b; ++k) s += partials[k];
        for (int k = 0; k < 16; ++k) { woff[k] = s; s += wsum[k]; }
    }
    __syncthreads();
    int excl = woff[w] + v - d;
    if (i < NV) {
        ptr[i] = excl;
        cursor[i] = excl;
        dinv[i] = rsqrtf((float)d + 2.0f);   // SELF_LOOP_W = 2
        if (i == NV - 1) ptr[NV] = excl + d;
    }
}

// edat[p] = (source row, norm = dinv[row]*dinv[col])
__global__ void fill_kernel(const int* __restrict__ tei, const float* __restrict__ dinv,
                            int* __restrict__ cursor, int2* __restrict__ edat) {
    int e = blockIdx.x * blockDim.x + threadIdx.x;
    if (e < ETR) {
        int row = tei[e];
        int col = tei[ETR + e];
        int p = atomicAdd(&cursor[col], 1);
        edat[p] = make_int2(row, __float_as_int(dinv[row] * dinv[col]));
    }
}

// ---------------- converts ----------------

__global__ void cvt_x_kernel(const float* __restrict__ x, unsigned short* __restrict__ xb, int n4) {
    int i = blockIdx.x * blockDim.x + threadIdx.x;
    if (i < n4) {
        float4 v = *(const float4*)&x[i * 4];
        union { unsigned short u[4]; uint2 q; } o;
        o.u[0] = f2b(v.x); o.u[1] = f2b(v.y); o.u[2] = f2b(v.z); o.u[3] = f2b(v.w);
        *(uint2*)&xb[i * 4] = o.q;
    }
}

// Wt[n][k] = bf16(W[k][n])
__global__ void cvt_wt_kernel(const float* __restrict__ W, unsigned short* __restrict__ Wt,
                              int K, int N) {
    int idx = blockIdx.x * blockDim.x + threadIdx.x;
    if (idx < N * K) {
        int n = idx / K, k = idx - n * K;
        Wt[idx] = f2b(W[k * N + n]);
    }
}

// ---------------- bf16 MFMA GEMM: slice-major C out ----------------
// C stored as [N/32][NV][32] bf16 so each 32-feat slice is contiguous (3.2MB).

template<int N, int K>
__global__ __launch_bounds__(256) void mfma_gemm_kernel(
    const unsigned short* __restrict__ A, const unsigned short* __restrict__ Bt,
    unsigned short* __restrict__ C, int M)
{
    constexpr int BK = 64;
    __shared__ unsigned short Asm[128][BK];
    __shared__ unsigned short Bsm[128][BK];
    int tid = threadIdx.x;
    int lane = tid & 63, wid = tid >> 6;
    int wr = wid >> 1, wc = wid & 1;
    int row0 = blockIdx.x * 128, col0 = blockIdx.y * 128;

    int sr = tid >> 3;
    int s8 = tid & 7;
    int sswz = s8 ^ (sr & 7);
    int fr = lane & 15;
    int g  = lane >> 4;

    f32x4 acc[4][4] = {};

    for (int k0 = 0; k0 < K; k0 += BK) {
        #pragma unroll
        for (int i = 0; i < 4; ++i) {
            int r = sr + i * 32;
            int gr = row0 + r;
            ushortx8 va = {0, 0, 0, 0, 0, 0, 0, 0};
            if (gr < M) va = *(const ushortx8*)&A[(size_t)gr * K + k0 + s8 * 8];
            *(ushortx8*)&Asm[r][sswz * 8] = va;
            ushortx8 vb = *(const ushortx8*)&Bt[(size_t)(col0 + r) * K + k0 + s8 * 8];
            *(ushortx8*)&Bsm[r][sswz * 8] = vb;
        }
        __syncthreads();
        #pragma unroll
        for (int kf = 0; kf < BK; kf += 32) {
            int sbase = kf >> 3;
            bf16x8 af[4], bfr[4];
            #pragma unroll
            for (int m = 0; m < 4; ++m) {
                int rr = wr * 64 + m * 16 + fr;
                af[m] = *(const bf16x8*)&Asm[rr][((sbase + g) ^ (fr & 7)) * 8];
            }
            #pragma unroll
            for (int n = 0; n < 4; ++n) {
                int rr = wc * 64 + n * 16 + fr;
                bfr[n] = *(const bf16x8*)&Bsm[rr][((sbase + g) ^ (fr & 7)) * 8];
            }
            #pragma unroll
            for (int m = 0; m < 4; ++m)
                #pragma unroll
                for (int n = 0; n < 4; ++n)
                    acc[m][n] = __builtin_amdgcn_mfma_f32_16x16x32_bf16(af[m], bfr[n], acc[m][n], 0, 0, 0);
        }
        __syncthreads();
    }

    // C/D layout: col = lane&15, row = (lane>>4)*4 + j ; slice-major store
    #pragma unroll
    for (int m = 0; m < 4; ++m) {
        int rbase = row0 + wr * 64 + m * 16 + g * 4;
        #pragma unroll
        for (int j = 0; j < 4; ++j) {
            int r = rbase + j;
            if (r < M) {
                #pragma unroll
                for (int n = 0; n < 4; ++n) {
                    int c = col0 + wc * 64 + n * 16 + fr;
                    size_t addr = ((size_t)(c >> 5) * NV + r) * 32 + (c & 31);
                    C[addr] = f2b(acc[m][n][j]);
                }
            }
        }
    }
}

// ---------------- XCD-pinned sliced gather ----------------
// hsl: slice-major [NQ][NV][32] bf16. Each physical XCD (HW_REG_XCC_ID) drains
// its own slice queue -> 3.2MB contiguous working set, resident in that XCD's
// 4MB L2. After own queue: sweep others (correctness never depends on XCC_ID).
// Block chunk = 64 nodes; wave quad (16 lanes) per node, 2 feats/lane.

template<int F, int NQ, bool RELU>
__global__ __launch_bounds__(256) void gather_q_kernel(
    const int* __restrict__ ptr, const int2* __restrict__ edat,
    const float* __restrict__ dinv, const unsigned short* __restrict__ hsl,
    const float* __restrict__ bias, unsigned short* __restrict__ hout,
    int* __restrict__ qc)
{
    constexpr int NCHUNK = (NV + 63) / 64;
    int xcd;
    asm volatile("s_getreg_b32 %0, hwreg(20, 0, 32)" : "=s"(xcd));
    xcd &= (NQ - 1);
    int tid = threadIdx.x;
    int lane = tid & 63, wv = tid >> 6;
    int sub = lane >> 4, fl = lane & 15;
    __shared__ int ch_s;
    const long long* edl = (const long long*)edat;

    for (int qq = 0; qq < NQ; ++qq) {
        int q = (xcd + qq) & (NQ - 1);
        const unsigned short* hb = hsl + (size_t)q * NV * 32 + fl * 2;
        float2 bv = *(const float2*)&bias[q * 32 + fl * 2];
        while (true) {
            if (tid == 0) ch_s = atomicAdd(&qc[q], 1);
            __syncthreads();
            int chunk = ch_s;
            __syncthreads();
            if (chunk >= NCHUNK) break;
            #pragma unroll
            for (int nn = 0; nn < 4; ++nn) {
                int node = chunk * 64 + wv * 16 + nn * 4 + sub;
                if (node >= NV) continue;
                float dc = dinv[node];
                int j0 = ptr[node], j1 = ptr[node + 1];
                float a0 = 0.f, a1 = 0.f;
                int j = j0;
                for (; j + 3 < j1; j += 4) {   // 4 independent 64B reads in flight
                    long long e0 = __builtin_nontemporal_load(edl + j);
                    long long e1 = __builtin_nontemporal_load(edl + j + 1);
                    long long e2 = __builtin_nontemporal_load(edl + j + 2);
                    long long e3 = __builtin_nontemporal_load(edl + j + 3);
                    float n0 = __int_as_float((int)(e0 >> 32));
                    float n1 = __int_as_float((int)(e1 >> 32));
                    float n2 = __int_as_float((int)(e2 >> 32));
                    float n3 = __int_as_float((int)(e3 >> 32));
                    unsigned u0 = *(const unsigned*)(hb + (size_t)(int)e0 * 32);
                    unsigned u1 = *(const unsigned*)(hb + (size_t)(int)e1 * 32);
                    unsigned u2 = *(const unsigned*)(hb + (size_t)(int)e2 * 32);
                    unsigned u3 = *(const unsigned*)(hb + (size_t)(int)e3 * 32);
                    a0 += n0 * blo(u0) + n1 * blo(u1) + n2 * blo(u2) + n3 * blo(u3);
                    a1 += n0 * bhi(u0) + n1 * bhi(u1) + n2 * bhi(u2) + n3 * bhi(u3);
                }
                for (; j < j1; ++j) {
                    long long e0 = __builtin_nontemporal_load(edl + j);
                    float n0 = __int_as_float((int)(e0 >> 32));
                    unsigned u0 = *(const unsigned*)(hb + (size_t)(int)e0 * 32);
                    a0 += n0 * blo(u0);
                    a1 += n0 * bhi(u0);
                }
                unsigned us = *(const unsigned*)(hb + (size_t)node * 32);
                float sw = 2.0f * dc * dc;
                float o0 = a0 + sw * blo(us) + bv.x;
                float o1 = a1 + sw * bhi(us) + bv.y;
                if (RELU) { o0 = fmaxf(o0, 0.f); o1 = fmaxf(o1, 0.f); }
                union { unsigned short u2s[2]; unsigned w; } pk;
                pk.u2s[0] = f2b(o0); pk.u2s[1] = f2b(o1);
                __builtin_nontemporal_store(pk.w,
                    (unsigned*)(hout + (size_t)node * F + q * 32 + fl * 2));
            }
        }
    }
}

// ---------------- edge MLP via MFMA ----------------

__global__ __launch_bounds__(256) void edge_mlp_mfma_kernel(
    const int* __restrict__ pos, const int* __restrict__ neg,
    const unsigned short* __restrict__ h2, const unsigned short* __restrict__ Wl1t,
    const float* __restrict__ bl1, const float* __restrict__ Wl2,
    const float* __restrict__ bl2, float* __restrict__ out)
{
    __shared__ unsigned short Es[128][128];
    __shared__ unsigned short Ws[64][128];
    int tid = threadIdx.x;
    int lane = tid & 63, w = tid >> 6;
    int fr = lane & 15, g = lane >> 4;
    int e0 = blockIdx.x * 128;

    #pragma unroll
    for (int k = 0; k < 4; ++k) {
        int chunk = tid + k * 256;
        int row = chunk >> 4, c = chunk & 15;
        *(ushortx8*)&Ws[row][(c ^ (row & 7)) * 8] = *(const ushortx8*)&Wl1t[chunk * 8];
    }

    int et = tid >> 1, hh = tid & 1;
    int eg = e0 + et;
    int a, b;
    if (eg < EPOS) { a = pos[eg]; b = pos[EPOS + eg]; }
    else { int i = eg - EPOS; a = neg[i]; b = neg[EPOS + i]; }
    const unsigned short* pa = h2 + (size_t)a * 128 + hh * 64;
    const unsigned short* pb = h2 + (size_t)b * 128 + hh * 64;
    #pragma unroll
    for (int c8 = 0; c8 < 8; ++c8) {
        ushortx8 va = *(const ushortx8*)&pa[c8 * 8];
        ushortx8 vb = *(const ushortx8*)&pb[c8 * 8];
        ushortx8 vs = bf16add8(va, vb);
        int c = hh * 8 + c8;
        *(ushortx8*)&Es[et][(c ^ (et & 7)) * 8] = vs;
    }
    __syncthreads();

    f32x4 acc[2][4] = {};
    #pragma unroll
    for (int ks = 0; ks < 4; ++ks) {
        int c = ks * 4 + g;
        bf16x8 af[2], bfr[4];
        #pragma unroll
        for (int m = 0; m < 2; ++m) {
            int r = w * 32 + m * 16 + fr;
            af[m] = *(const bf16x8*)&Es[r][(c ^ (r & 7)) * 8];
        }
        #pragma unroll
        for (int n = 0; n < 4; ++n) {
            int r = n * 16 + fr;
            bfr[n] = *(const bf16x8*)&Ws[r][(c ^ (r & 7)) * 8];
        }
        #pragma unroll
        for (int m = 0; m < 2; ++m)
            #pragma unroll
            for (int n = 0; n < 4; ++n)
                acc[m][n] = __builtin_amdgcn_mfma_f32_16x16x32_bf16(af[m], bfr[n], acc[m][n], 0, 0, 0);
    }

    float bl2v = bl2[0];
    float b1v[4], w2v[4];
    #pragma unroll
    for (int n = 0; n < 4; ++n) {
        b1v[n] = bl1[n * 16 + fr];
        w2v[n] = Wl2[n * 16 + fr];
    }
    #pragma unroll
    for (int m = 0; m < 2; ++m) {
        float p[4];
        #pragma unroll
        for (int j = 0; j < 4; ++j) {
            float s = 0.f;
            #pragma unroll
            for (int n = 0; n < 4; ++n)
                s += fmaxf(acc[m][n][j] + b1v[n], 0.0f) * w2v[n];
            p[j] = s;
        }
        #pragma unroll
        for (int off = 1; off < 16; off <<= 1) {
            #pragma unroll
            for (int j = 0; j < 4; ++j)
                p[j] += __shfl_xor(p[j], off);
        }
        int ebase = e0 + w * 32 + m * 16 + g * 4;
        #pragma unroll
        for (int j = 0; j < 4; ++j)
            if (fr == j)
                out[ebase + j] = 1.0f / (1.0f + expf(-(p[j] + bl2v)));
    }
}

// ---------------- launch ----------------

extern "C" void kernel_launch(void* const* d_in, const int* in_sizes, int n_in,
                              void* d_out, int out_size, void* d_ws, size_t ws_size,
                              hipStream_t stream) {
    const float* x   = (const float*)d_in[0];
    const int*   tei = (const int*)d_in[1];
    const int*   pos = (const int*)d_in[2];
    const int*   neg = (const int*)d_in[3];
    const float* W1  = (const float*)d_in[4];
    const float* b1  = (const float*)d_in[5];
    const float* W2  = (const float*)d_in[6];
    const float* b2  = (const float*)d_in[7];
    const float* Wl1 = (const float*)d_in[8];
    const float* bl1 = (const float*)d_in[9];
    const float* Wl2 = (const float*)d_in[10];
    const float* bl2 = (const float*)d_in[11];
    float* out = (float*)d_out;

    // workspace (4B-word offsets)
    float* fws = (float*)d_ws;
    int*   iws = (int*)d_ws;
    unsigned short* usws = (unsigned short*)d_ws;
    float* dinv     = fws;                         // [50000]
    int*   deg      = iws + 50000;                 // [50000]
    int*   ptr      = iws + 100000;                // [50001]
    int*   cursor   = iws + 150002;                // [50000]
    int2*  edat     = (int2*)(iws + 200064);       // [800000] int2 -> ends 1800064
    int*   partials = iws + 1800064;               // [64] -> ends 1800128
    int*   qc       = iws + 1800128;               // [16] queue tickets (g1: 0..7, g2: 8..11)
    unsigned short* w1t  = usws + 2ull * 1800192;  // [256*256]
    unsigned short* w2t  = usws + 2ull * 1832960;  // [128*256]
    unsigned short* wl1t = usws + 2ull * 1849344;  // [64*128]
    unsigned short* bufX = usws + 2ull * 1853504;  // 12.8M ushorts: xb, then h2lin (slice-major)
    unsigned short* bufL16 = usws + 2ull * 8253504;  // h1lin (slice-major), then h2 row-major
    unsigned short* bufH = usws + 2ull * 14653504;   // h1 bf16 row-major

    hipMemsetAsync(deg, 0, NV * sizeof(int), stream);
    hipMemsetAsync(qc, 0, 16 * sizeof(int), stream);

    deg_kernel<<<(ETR + 255) / 256, 256, 0, stream>>>(tei, deg);
    partial_kernel<<<49, 1024, 0, stream>>>(deg, partials);
    ptr_kernel<<<49, 1024, 0, stream>>>(deg, partials, ptr, cursor, dinv);
    fill_kernel<<<(ETR + 255) / 256, 256, 0, stream>>>(tei, dinv, cursor, edat);

    cvt_x_kernel<<<(NV * 256 / 4 + 255) / 256, 256, 0, stream>>>(x, bufX, NV * 256 / 4);
    cvt_wt_kernel<<<(256 * 256 + 255) / 256, 256, 0, stream>>>(W1, w1t, 256, 256);
    cvt_wt_kernel<<<(128 * 256 + 255) / 256, 256, 0, stream>>>(W2, w2t, 256, 128);
    cvt_wt_kernel<<<(64 * 128 + 255) / 256, 256, 0, stream>>>(Wl1, wl1t, 128, 64);

    // layer 1: h1lin slice-major[8] -> XCD-pinned gather -> h1 row-major
    mfma_gemm_kernel<256, 256><<<dim3(391, 2), 256, 0, stream>>>(bufX, w1t, bufL16, NV);
    gather_q_kernel<256, 8, true><<<1024, 256, 0, stream>>>(ptr, edat, dinv, bufL16, b1, bufH, qc);

    // layer 2: h2lin slice-major[4] (overwrites bufX) -> gather -> h2 row-major (bufL16)
    mfma_gemm_kernel<128, 256><<<dim3(391, 1), 256, 0, stream>>>(bufH, w2t, bufX, NV);
    gather_q_kernel<128, 4, false><<<1024, 256, 0, stream>>>(ptr, edat, dinv, bufX, b2, bufL16, qc + 8);

    // edge MLP head (MFMA)
    edge_mlp_mfma_kernel<<<ETEST / 128, 256, 0, stream>>>(pos, neg, bufL16, wl1t, bl1, Wl2, bl2, out);
}

// Round 9
// 298.082 us; speedup vs baseline: 2.0246x; 2.0246x over previous
//
#include <hip/hip_runtime.h>
#include <math.h>

#define NV 50000
#define ETR 800000
#define EPOS 200000
#define ETEST 400000

typedef __attribute__((ext_vector_type(8))) short bf16x8;
typedef __attribute__((ext_vector_type(8))) unsigned short ushortx8;
typedef __attribute__((ext_vector_type(4))) float f32x4;

__device__ inline unsigned short f2b(float f) {
    union { float f; unsigned u; } v; v.f = f;
    unsigned r = v.u + 0x7fffu + ((v.u >> 16) & 1u);   // RNE
    return (unsigned short)(r >> 16);
}
__device__ inline float blo(unsigned q) { union { unsigned u; float f; } v; v.u = q << 16; return v.f; }
__device__ inline float bhi(unsigned q) { union { unsigned u; float f; } v; v.u = q & 0xffff0000u; return v.f; }
__device__ inline float b2f(unsigned short s) { union { unsigned u; float f; } v; v.u = ((unsigned)s) << 16; return v.f; }

__device__ inline ushortx8 bf16add8(ushortx8 a, ushortx8 b) {
    ushortx8 r;
    #pragma unroll
    for (int i = 0; i < 8; ++i)
        r[i] = f2b(b2f(a[i]) + b2f(b[i]));
    return r;
}

// ---------------- CSR build ----------------

__global__ void deg_kernel(const int* __restrict__ tei, int* __restrict__ deg) {
    int e = blockIdx.x * blockDim.x + threadIdx.x;
    if (e < ETR) atomicAdd(&deg[tei[ETR + e]], 1);
}

__global__ __launch_bounds__(1024) void partial_kernel(const int* __restrict__ deg,
                                                       int* __restrict__ partials) {
    int i = blockIdx.x * 1024 + threadIdx.x;
    int v = (i < NV) ? deg[i] : 0;
    #pragma unroll
    for (int off = 32; off > 0; off >>= 1) v += __shfl_xor(v, off);
    __shared__ int wsum[16];
    if ((threadIdx.x & 63) == 0) wsum[threadIdx.x >> 6] = v;
    __syncthreads();
    if (threadIdx.x == 0) {
        int s = 0;
        #pragma unroll
        for (int k = 0; k < 16; ++k) s += wsum[k];
        partials[blockIdx.x] = s;
    }
}

__global__ __launch_bounds__(1024) void ptr_kernel(
    const int* __restrict__ deg, const int* __restrict__ partials,
    int* __restrict__ ptr, int* __restrict__ cursor, float* __restrict__ dinv)
{
    int b = blockIdx.x, t = threadIdx.x;
    int i = b * 1024 + t;
    int d = (i < NV) ? deg[i] : 0;
    int lane = t & 63, w = t >> 6;
    int v = d;
    #pragma unroll
    for (int off = 1; off < 64; off <<= 1) {
        int u = __shfl_up(v, off);
        if (lane >= off) v += u;
    }
    __shared__ int wsum[16], woff[16];
    if (lane == 63) wsum[w] = v;
    __syncthreads();
    if (t == 0) {
        int s = 0;
        for (int k = 0; k < b; ++k) s += partials[k];
        for (int k = 0; k < 16; ++k) { woff[k] = s; s += wsum[k]; }
    }
    __syncthreads();
    int excl = woff[w] + v - d;
    if (i < NV) {
        ptr[i] = excl;
        cursor[i] = excl;
        dinv[i] = rsqrtf((float)d + 2.0f);   // SELF_LOOP_W = 2
        if (i == NV - 1) ptr[NV] = excl + d;
    }
}

// edat[p] = (source row, norm = dinv[row]*dinv[col])
__global__ void fill_kernel(const int* __restrict__ tei, const float* __restrict__ dinv,
                            int* __restrict__ cursor, int2* __restrict__ edat) {
    int e = blockIdx.x * blockDim.x + threadIdx.x;
    if (e < ETR) {
        int row = tei[e];
        int col = tei[ETR + e];
        int p = atomicAdd(&cursor[col], 1);
        edat[p] = make_int2(row, __float_as_int(dinv[row] * dinv[col]));
    }
}

// ---------------- combined weight transpose+convert (1 launch) ----------------
// Wt[n][k] = bf16(W[k][n]) for W1[256x256], W2[256x128], Wl1[128x64]

__global__ void cvt_wt_all_kernel(const float* __restrict__ W1, const float* __restrict__ W2,
                                  const float* __restrict__ Wl1,
                                  unsigned short* __restrict__ w1t, unsigned short* __restrict__ w2t,
                                  unsigned short* __restrict__ wl1t) {
    int idx = blockIdx.x * blockDim.x + threadIdx.x;
    if (idx < 65536) {
        int n = idx >> 8, k = idx & 255;
        w1t[idx] = f2b(W1[k * 256 + n]);
    } else if (idx < 98304) {
        int i = idx - 65536;
        int n = i >> 8, k = i & 255;
        w2t[i] = f2b(W2[k * 128 + n]);
    } else if (idx < 106496) {
        int i = idx - 98304;
        int n = i >> 7, k = i & 127;
        wl1t[i] = f2b(Wl1[k * 64 + n]);
    }
}

// ---------------- bf16 MFMA GEMM: C[M][N] = A[M][K] @ Bt[N][K]^T ----------------
// 128x128 tile, 4 waves in 2x2, BK=64, 16x16x32 MFMA, XOR-swizzled LDS (T2).
// AF32: A is f32, converted to bf16 in registers during staging (fuses cvt_x).

template<int N, int K, bool AF32>
__global__ __launch_bounds__(256) void mfma_gemm_kernel(
    const void* __restrict__ Av, const unsigned short* __restrict__ Bt,
    unsigned short* __restrict__ C, int M)
{
    constexpr int BK = 64;
    __shared__ unsigned short Asm[128][BK];
    __shared__ unsigned short Bsm[128][BK];
    int tid = threadIdx.x;
    int lane = tid & 63, wid = tid >> 6;
    int wr = wid >> 1, wc = wid & 1;
    int row0 = blockIdx.x * 128, col0 = blockIdx.y * 128;

    int sr = tid >> 3;
    int s8 = tid & 7;
    int sswz = s8 ^ (sr & 7);
    int fr = lane & 15;
    int g  = lane >> 4;

    f32x4 acc[4][4] = {};

    for (int k0 = 0; k0 < K; k0 += BK) {
        #pragma unroll
        for (int i = 0; i < 4; ++i) {
            int r = sr + i * 32;
            int gr = row0 + r;
            ushortx8 va = {0, 0, 0, 0, 0, 0, 0, 0};
            if constexpr (AF32) {
                const float* Af = (const float*)Av;
                if (gr < M) {
                    float4 f0 = *(const float4*)&Af[(size_t)gr * K + k0 + s8 * 8];
                    float4 f1 = *(const float4*)&Af[(size_t)gr * K + k0 + s8 * 8 + 4];
                    va[0] = f2b(f0.x); va[1] = f2b(f0.y); va[2] = f2b(f0.z); va[3] = f2b(f0.w);
                    va[4] = f2b(f1.x); va[5] = f2b(f1.y); va[6] = f2b(f1.z); va[7] = f2b(f1.w);
                }
            } else {
                const unsigned short* Ab = (const unsigned short*)Av;
                if (gr < M) va = *(const ushortx8*)&Ab[(size_t)gr * K + k0 + s8 * 8];
            }
            *(ushortx8*)&Asm[r][sswz * 8] = va;
            ushortx8 vb = *(const ushortx8*)&Bt[(size_t)(col0 + r) * K + k0 + s8 * 8];
            *(ushortx8*)&Bsm[r][sswz * 8] = vb;
        }
        __syncthreads();
        #pragma unroll
        for (int kf = 0; kf < BK; kf += 32) {
            int sbase = kf >> 3;
            bf16x8 af[4], bfr[4];
            #pragma unroll
            for (int m = 0; m < 4; ++m) {
                int rr = wr * 64 + m * 16 + fr;
                af[m] = *(const bf16x8*)&Asm[rr][((sbase + g) ^ (fr & 7)) * 8];
            }
            #pragma unroll
            for (int n = 0; n < 4; ++n) {
                int rr = wc * 64 + n * 16 + fr;
                bfr[n] = *(const bf16x8*)&Bsm[rr][((sbase + g) ^ (fr & 7)) * 8];
            }
            #pragma unroll
            for (int m = 0; m < 4; ++m)
                #pragma unroll
                for (int n = 0; n < 4; ++n)
                    acc[m][n] = __builtin_amdgcn_mfma_f32_16x16x32_bf16(af[m], bfr[n], acc[m][n], 0, 0, 0);
        }
        __syncthreads();
    }

    // C/D layout: col = lane&15, row = (lane>>4)*4 + j
    #pragma unroll
    for (int m = 0; m < 4; ++m) {
        int rbase = row0 + wr * 64 + m * 16 + g * 4;
        #pragma unroll
        for (int j = 0; j < 4; ++j) {
            int r = rbase + j;
            if (r < M) {
                #pragma unroll
                for (int n = 0; n < 4; ++n) {
                    int c = col0 + wc * 64 + n * 16 + fr;
                    C[(size_t)r * N + c] = f2b(acc[m][n][j]);
                }
            }
        }
    }
}

// ---------------- gather (bf16 in/out), 8-way edge unroll + NT stores ----------------
// One wave per node; V = F/64 bf16 per lane (whole row per wave, coalesced).

template<int F, bool RELU>
__global__ __launch_bounds__(256) void gather_kernel(
    const int* __restrict__ ptr, const int2* __restrict__ edat,
    const float* __restrict__ dinv, const unsigned short* __restrict__ hlin,
    const float* __restrict__ bias, unsigned short* __restrict__ hout)
{
    constexpr int V = F / 64;
    int gid = blockIdx.x * blockDim.x + threadIdx.x;
    int node = gid >> 6, lane = gid & 63;
    if (node >= NV) return;
    float dc = dinv[node];
    int j0 = ptr[node], j1 = ptr[node + 1];
    float acc[V] = {};
    const unsigned short* hb = hlin + lane * V;
    const long long* edl = (const long long*)edat;

    int j = j0;
    for (; j + 7 < j1; j += 8) {            // 8 independent row loads in flight
        long long e[8];
        #pragma unroll
        for (int u = 0; u < 8; ++u) e[u] = __builtin_nontemporal_load(edl + j + u);
        if constexpr (V == 4) {
            uint2 q[8];
            #pragma unroll
            for (int u = 0; u < 8; ++u)
                q[u] = *(const uint2*)(hb + (size_t)(int)e[u] * F);
            #pragma unroll
            for (int u = 0; u < 8; ++u) {
                float n = __int_as_float((int)(e[u] >> 32));
                acc[0] += n * blo(q[u].x);
                acc[1] += n * bhi(q[u].x);
                acc[2] += n * blo(q[u].y);
                acc[3] += n * bhi(q[u].y);
            }
        } else {
            unsigned q[8];
            #pragma unroll
            for (int u = 0; u < 8; ++u)
                q[u] = *(const unsigned*)(hb + (size_t)(int)e[u] * F);
            #pragma unroll
            for (int u = 0; u < 8; ++u) {
                float n = __int_as_float((int)(e[u] >> 32));
                acc[0] += n * blo(q[u]);
                acc[1] += n * bhi(q[u]);
            }
        }
    }
    for (; j + 3 < j1; j += 4) {
        long long e[4];
        #pragma unroll
        for (int u = 0; u < 4; ++u) e[u] = __builtin_nontemporal_load(edl + j + u);
        if constexpr (V == 4) {
            uint2 q[4];
            #pragma unroll
            for (int u = 0; u < 4; ++u)
                q[u] = *(const uint2*)(hb + (size_t)(int)e[u] * F);
            #pragma unroll
            for (int u = 0; u < 4; ++u) {
                float n = __int_as_float((int)(e[u] >> 32));
                acc[0] += n * blo(q[u].x);
                acc[1] += n * bhi(q[u].x);
                acc[2] += n * blo(q[u].y);
                acc[3] += n * bhi(q[u].y);
            }
        } else {
            unsigned q[4];
            #pragma unroll
            for (int u = 0; u < 4; ++u)
                q[u] = *(const unsigned*)(hb + (size_t)(int)e[u] * F);
            #pragma unroll
            for (int u = 0; u < 4; ++u) {
                float n = __int_as_float((int)(e[u] >> 32));
                acc[0] += n * blo(q[u]);
                acc[1] += n * bhi(q[u]);
            }
        }
    }
    for (; j < j1; ++j) {
        long long e0 = __builtin_nontemporal_load(edl + j);
        float n0 = __int_as_float((int)(e0 >> 32));
        if constexpr (V == 4) {
            uint2 q0 = *(const uint2*)(hb + (size_t)(int)e0 * F);
            acc[0] += n0 * blo(q0.x);
            acc[1] += n0 * bhi(q0.x);
            acc[2] += n0 * blo(q0.y);
            acc[3] += n0 * bhi(q0.y);
        } else {
            unsigned q0 = *(const unsigned*)(hb + (size_t)(int)e0 * F);
            acc[0] += n0 * blo(q0);
            acc[1] += n0 * bhi(q0);
        }
    }

    // self-loop (weight 2, norm dc^2) + bias (+relu); NT store keeps h table in L2
    const unsigned short* ps = hb + (size_t)node * F;
    float sw = 2.0f * dc * dc;
    if constexpr (V == 4) {
        uint2 qs = *(const uint2*)ps;
        float o0 = acc[0] + sw * blo(qs.x) + bias[lane * 4 + 0];
        float o1 = acc[1] + sw * bhi(qs.x) + bias[lane * 4 + 1];
        float o2 = acc[2] + sw * blo(qs.y) + bias[lane * 4 + 2];
        float o3 = acc[3] + sw * bhi(qs.y) + bias[lane * 4 + 3];
        if (RELU) {
            o0 = fmaxf(o0, 0.f); o1 = fmaxf(o1, 0.f);
            o2 = fmaxf(o2, 0.f); o3 = fmaxf(o3, 0.f);
        }
        union { unsigned short u[4]; unsigned long long ll; } pk;
        pk.u[0] = f2b(o0); pk.u[1] = f2b(o1); pk.u[2] = f2b(o2); pk.u[3] = f2b(o3);
        __builtin_nontemporal_store(pk.ll, (unsigned long long*)(hout + (size_t)node * F + lane * 4));
    } else {
        unsigned qs = *(const unsigned*)ps;
        float o0 = acc[0] + sw * blo(qs) + bias[lane * 2 + 0];
        float o1 = acc[1] + sw * bhi(qs) + bias[lane * 2 + 1];
        if (RELU) { o0 = fmaxf(o0, 0.f); o1 = fmaxf(o1, 0.f); }
        union { unsigned short u[2]; unsigned q; } pk;
        pk.u[0] = f2b(o0); pk.u[1] = f2b(o1);
        __builtin_nontemporal_store(pk.q, (unsigned*)(hout + (size_t)node * F + lane * 2));
    }
}

// ---------------- edge MLP via MFMA ----------------

__global__ __launch_bounds__(256) void edge_mlp_mfma_kernel(
    const int* __restrict__ pos, const int* __restrict__ neg,
    const unsigned short* __restrict__ h2, const unsigned short* __restrict__ Wl1t,
    const float* __restrict__ bl1, const float* __restrict__ Wl2,
    const float* __restrict__ bl2, float* __restrict__ out)
{
    __shared__ unsigned short Es[128][128];
    __shared__ unsigned short Ws[64][128];
    int tid = threadIdx.x;
    int lane = tid & 63, w = tid >> 6;
    int fr = lane & 15, g = lane >> 4;
    int e0 = blockIdx.x * 128;

    #pragma unroll
    for (int k = 0; k < 4; ++k) {
        int chunk = tid + k * 256;
        int row = chunk >> 4, c = chunk & 15;
        *(ushortx8*)&Ws[row][(c ^ (row & 7)) * 8] = *(const ushortx8*)&Wl1t[chunk * 8];
    }

    int et = tid >> 1, hh = tid & 1;
    int eg = e0 + et;
    int a, b;
    if (eg < EPOS) { a = pos[eg]; b = pos[EPOS + eg]; }
    else { int i = eg - EPOS; a = neg[i]; b = neg[EPOS + i]; }
    const unsigned short* pa = h2 + (size_t)a * 128 + hh * 64;
    const unsigned short* pb = h2 + (size_t)b * 128 + hh * 64;
    #pragma unroll
    for (int c8 = 0; c8 < 8; ++c8) {
        ushortx8 va = *(const ushortx8*)&pa[c8 * 8];
        ushortx8 vb = *(const ushortx8*)&pb[c8 * 8];
        ushortx8 vs = bf16add8(va, vb);
        int c = hh * 8 + c8;
        *(ushortx8*)&Es[et][(c ^ (et & 7)) * 8] = vs;
    }
    __syncthreads();

    f32x4 acc[2][4] = {};
    #pragma unroll
    for (int ks = 0; ks < 4; ++ks) {
        int c = ks * 4 + g;
        bf16x8 af[2], bfr[4];
        #pragma unroll
        for (int m = 0; m < 2; ++m) {
            int r = w * 32 + m * 16 + fr;
            af[m] = *(const bf16x8*)&Es[r][(c ^ (r & 7)) * 8];
        }
        #pragma unroll
        for (int n = 0; n < 4; ++n) {
            int r = n * 16 + fr;
            bfr[n] = *(const bf16x8*)&Ws[r][(c ^ (r & 7)) * 8];
        }
        #pragma unroll
        for (int m = 0; m < 2; ++m)
            #pragma unroll
            for (int n = 0; n < 4; ++n)
                acc[m][n] = __builtin_amdgcn_mfma_f32_16x16x32_bf16(af[m], bfr[n], acc[m][n], 0, 0, 0);
    }

    float bl2v = bl2[0];
    float b1v[4], w2v[4];
    #pragma unroll
    for (int n = 0; n < 4; ++n) {
        b1v[n] = bl1[n * 16 + fr];
        w2v[n] = Wl2[n * 16 + fr];
    }
    #pragma unroll
    for (int m = 0; m < 2; ++m) {
        float p[4];
        #pragma unroll
        for (int j = 0; j < 4; ++j) {
            float s = 0.f;
            #pragma unroll
            for (int n = 0; n < 4; ++n)
                s += fmaxf(acc[m][n][j] + b1v[n], 0.0f) * w2v[n];
            p[j] = s;
        }
        #pragma unroll
        for (int off = 1; off < 16; off <<= 1) {
            #pragma unroll
            for (int j = 0; j < 4; ++j)
                p[j] += __shfl_xor(p[j], off);
        }
        int ebase = e0 + w * 32 + m * 16 + g * 4;
        #pragma unroll
        for (int j = 0; j < 4; ++j)
            if (fr == j)
                out[ebase + j] = 1.0f / (1.0f + expf(-(p[j] + bl2v)));
    }
}

// ---------------- launch ----------------

extern "C" void kernel_launch(void* const* d_in, const int* in_sizes, int n_in,
                              void* d_out, int out_size, void* d_ws, size_t ws_size,
                              hipStream_t stream) {
    const float* x   = (const float*)d_in[0];
    const int*   tei = (const int*)d_in[1];
    const int*   pos = (const int*)d_in[2];
    const int*   neg = (const int*)d_in[3];
    const float* W1  = (const float*)d_in[4];
    const float* b1  = (const float*)d_in[5];
    const float* W2  = (const float*)d_in[6];
    const float* b2  = (const float*)d_in[7];
    const float* Wl1 = (const float*)d_in[8];
    const float* bl1 = (const float*)d_in[9];
    const float* Wl2 = (const float*)d_in[10];
    const float* bl2 = (const float*)d_in[11];
    float* out = (float*)d_out;

    // workspace (4B-word offsets)
    float* fws = (float*)d_ws;
    int*   iws = (int*)d_ws;
    unsigned short* usws = (unsigned short*)d_ws;
    float* dinv     = fws;                         // [50000]
    int*   deg      = iws + 50000;                 // [50000]
    int*   ptr      = iws + 100000;                // [50001]
    int*   cursor   = iws + 150002;                // [50000]
    int2*  edat     = (int2*)(iws + 200064);       // [800000] int2 -> ends 1800064
    int*   partials = iws + 1800064;               // [64]
    unsigned short* w1t  = usws + 2ull * 1800192;  // [256*256]
    unsigned short* w2t  = usws + 2ull * 1832960;  // [128*256]
    unsigned short* wl1t = usws + 2ull * 1849344;  // [64*128]
    unsigned short* bufX = usws + 2ull * 1853504;  // h2lin bf16
    unsigned short* bufL16 = usws + 2ull * 8253504;  // h1lin bf16, then h2 bf16
    unsigned short* bufH = usws + 2ull * 14653504;   // h1 bf16

    hipMemsetAsync(deg, 0, NV * sizeof(int), stream);

    deg_kernel<<<(ETR + 255) / 256, 256, 0, stream>>>(tei, deg);
    partial_kernel<<<49, 1024, 0, stream>>>(deg, partials);
    ptr_kernel<<<49, 1024, 0, stream>>>(deg, partials, ptr, cursor, dinv);
    fill_kernel<<<(ETR + 255) / 256, 256, 0, stream>>>(tei, dinv, cursor, edat);
    cvt_wt_all_kernel<<<416, 256, 0, stream>>>(W1, W2, Wl1, w1t, w2t, wl1t);

    // layer 1: h1lin = bf16(x) @ w1t (cvt fused into staging)
    mfma_gemm_kernel<256, 256, true><<<dim3(391, 2), 256, 0, stream>>>(x, w1t, bufL16, NV);
    gather_kernel<256, true><<<(NV * 64) / 256, 256, 0, stream>>>(ptr, edat, dinv, bufL16, b1, bufH);

    // layer 2: h2lin = h1 @ w2t -> bufX; gather -> h2 (bufL16)
    mfma_gemm_kernel<128, 256, false><<<dim3(391, 1), 256, 0, stream>>>(bufH, w2t, bufX, NV);
    gather_kernel<128, false><<<(NV * 64) / 256, 256, 0, stream>>>(ptr, edat, dinv, bufX, b2, bufL16);

    // edge MLP head (MFMA)
    edge_mlp_mfma_kernel<<<ETEST / 128, 256, 0, stream>>>(pos, neg, bufL16, wl1t, bl1, Wl2, bl2, out);
}

// Round 10
// 291.712 us; speedup vs baseline: 2.0688x; 1.0218x over previous
//
#include <hip/hip_runtime.h>
#include <math.h>

#define NV 50000
#define ETR 800000
#define EPOS 200000
#define ETEST 400000

typedef __attribute__((ext_vector_type(8))) short bf16x8;
typedef __attribute__((ext_vector_type(8))) unsigned short ushortx8;
typedef __attribute__((ext_vector_type(4))) float f32x4;

__device__ inline unsigned short f2b(float f) {
    union { float f; unsigned u; } v; v.f = f;
    unsigned r = v.u + 0x7fffu + ((v.u >> 16) & 1u);   // RNE
    return (unsigned short)(r >> 16);
}
__device__ inline float blo(unsigned q) { union { unsigned u; float f; } v; v.u = q << 16; return v.f; }
__device__ inline float bhi(unsigned q) { union { unsigned u; float f; } v; v.u = q & 0xffff0000u; return v.f; }
__device__ inline float b2f(unsigned short s) { union { unsigned u; float f; } v; v.u = ((unsigned)s) << 16; return v.f; }

__device__ inline ushortx8 bf16add8(ushortx8 a, ushortx8 b) {
    ushortx8 r;
    #pragma unroll
    for (int i = 0; i < 8; ++i)
        r[i] = f2b(b2f(a[i]) + b2f(b[i]));
    return r;
}

// ---------------- shared GEMM body (128x128 tile, 4 waves 2x2, BK=64, swizzled LDS) ----------------

template<int N, int K, bool AF32>
__device__ __forceinline__ void gemm_body(
    const void* __restrict__ Av, const unsigned short* __restrict__ Bt,
    unsigned short* __restrict__ C, int M, int row0, int col0)
{
    constexpr int BK = 64;
    __shared__ unsigned short Asm[128][BK];
    __shared__ unsigned short Bsm[128][BK];
    int tid = threadIdx.x;
    int lane = tid & 63, wid = tid >> 6;
    int wr = wid >> 1, wc = wid & 1;

    int sr = tid >> 3;
    int s8 = tid & 7;
    int sswz = s8 ^ (sr & 7);
    int fr = lane & 15;
    int g  = lane >> 4;

    f32x4 acc[4][4] = {};

    for (int k0 = 0; k0 < K; k0 += BK) {
        #pragma unroll
        for (int i = 0; i < 4; ++i) {
            int r = sr + i * 32;
            int gr = row0 + r;
            ushortx8 va = {0, 0, 0, 0, 0, 0, 0, 0};
            if constexpr (AF32) {
                const float* Af = (const float*)Av;
                if (gr < M) {
                    float4 f0 = *(const float4*)&Af[(size_t)gr * K + k0 + s8 * 8];
                    float4 f1 = *(const float4*)&Af[(size_t)gr * K + k0 + s8 * 8 + 4];
                    va[0] = f2b(f0.x); va[1] = f2b(f0.y); va[2] = f2b(f0.z); va[3] = f2b(f0.w);
                    va[4] = f2b(f1.x); va[5] = f2b(f1.y); va[6] = f2b(f1.z); va[7] = f2b(f1.w);
                }
            } else {
                const unsigned short* Ab = (const unsigned short*)Av;
                if (gr < M) va = *(const ushortx8*)&Ab[(size_t)gr * K + k0 + s8 * 8];
            }
            *(ushortx8*)&Asm[r][sswz * 8] = va;
            ushortx8 vb = *(const ushortx8*)&Bt[(size_t)(col0 + r) * K + k0 + s8 * 8];
            *(ushortx8*)&Bsm[r][sswz * 8] = vb;
        }
        __syncthreads();
        #pragma unroll
        for (int kf = 0; kf < BK; kf += 32) {
            int sbase = kf >> 3;
            bf16x8 af[4], bfr[4];
            #pragma unroll
            for (int m = 0; m < 4; ++m) {
                int rr = wr * 64 + m * 16 + fr;
                af[m] = *(const bf16x8*)&Asm[rr][((sbase + g) ^ (fr & 7)) * 8];
            }
            #pragma unroll
            for (int n = 0; n < 4; ++n) {
                int rr = wc * 64 + n * 16 + fr;
                bfr[n] = *(const bf16x8*)&Bsm[rr][((sbase + g) ^ (fr & 7)) * 8];
            }
            #pragma unroll
            for (int m = 0; m < 4; ++m)
                #pragma unroll
                for (int n = 0; n < 4; ++n)
                    acc[m][n] = __builtin_amdgcn_mfma_f32_16x16x32_bf16(af[m], bfr[n], acc[m][n], 0, 0, 0);
        }
        __syncthreads();
    }

    // C/D layout: col = lane&15, row = (lane>>4)*4 + j
    #pragma unroll
    for (int m = 0; m < 4; ++m) {
        int rbase = row0 + wr * 64 + m * 16 + g * 4;
        #pragma unroll
        for (int j = 0; j < 4; ++j) {
            int r = rbase + j;
            if (r < M) {
                #pragma unroll
                for (int n = 0; n < 4; ++n) {
                    int c = col0 + wc * 64 + n * 16 + fr;
                    C[(size_t)r * N + c] = f2b(acc[m][n][j]);
                }
            }
        }
    }
}

// ---------------- fat0: deg histogram (blocks 0..3124) + cvt W1 (3125..3380) ----------------

__global__ __launch_bounds__(256) void fat0_kernel(
    const int* __restrict__ tei, int* __restrict__ deg,
    const float* __restrict__ W1, unsigned short* __restrict__ w1t)
{
    int bid = blockIdx.x;
    int t = threadIdx.x;
    if (bid < 3125) {
        int e = bid * 256 + t;
        if (e < ETR) atomicAdd(&deg[tei[ETR + e]], 1);
    } else {
        int i = (bid - 3125) * 256 + t;        // 0..65535
        int n = i >> 8, k = i & 255;
        w1t[i] = f2b(W1[k * 256 + n]);
    }
}

// ---------------- fat1: gemm1 (0..781) + partial (782..830) + cvt W2 (831..958) + cvt Wl1 (959..990) ----------------

__global__ __launch_bounds__(256) void fat1_kernel(
    const float* __restrict__ x, const unsigned short* __restrict__ w1t,
    unsigned short* __restrict__ h1lin,
    const int* __restrict__ deg, int* __restrict__ partials,
    const float* __restrict__ W2, unsigned short* __restrict__ w2t,
    const float* __restrict__ Wl1, unsigned short* __restrict__ wl1t)
{
    int bid = blockIdx.x;
    int t = threadIdx.x;
    if (bid < 782) {
        // adjacent blocks share the A row-panel (L2 reuse): col from low bit
        int row0 = (bid >> 1) * 128, col0 = (bid & 1) * 128;
        gemm_body<256, 256, true>(x, w1t, h1lin, NV, row0, col0);
    } else if (bid < 831) {
        int p = bid - 782;
        int base = p * 1024;
        int s = 0;
        #pragma unroll
        for (int k = 0; k < 4; ++k) {
            int i = base + t + k * 256;
            if (i < NV) s += deg[i];
        }
        #pragma unroll
        for (int off = 32; off > 0; off >>= 1) s += __shfl_xor(s, off);
        __shared__ int ws4[4];
        if ((t & 63) == 0) ws4[t >> 6] = s;
        __syncthreads();
        if (t == 0) partials[p] = ws4[0] + ws4[1] + ws4[2] + ws4[3];
    } else if (bid < 959) {
        int i = (bid - 831) * 256 + t;         // 0..32767
        int n = i >> 8, k = i & 255;
        w2t[i] = f2b(W2[k * 128 + n]);
    } else {
        int i = (bid - 959) * 256 + t;         // 0..8191
        int n = i >> 7, k = i & 127;
        wl1t[i] = f2b(Wl1[k * 64 + n]);
    }
}

// ---------------- ptr scan (49 blocks x 1024) ----------------

__global__ __launch_bounds__(1024) void ptr_kernel(
    const int* __restrict__ deg, const int* __restrict__ partials,
    int* __restrict__ ptr, int* __restrict__ cursor, float* __restrict__ dinv)
{
    int b = blockIdx.x, t = threadIdx.x;
    int i = b * 1024 + t;
    int d = (i < NV) ? deg[i] : 0;
    int lane = t & 63, w = t >> 6;
    int v = d;
    #pragma unroll
    for (int off = 1; off < 64; off <<= 1) {
        int u = __shfl_up(v, off);
        if (lane >= off) v += u;
    }
    __shared__ int wsum[16], woff[16];
    if (lane == 63) wsum[w] = v;
    __syncthreads();
    if (t == 0) {
        int s = 0;
        for (int k = 0; k < b; ++k) s += partials[k];
        for (int k = 0; k < 16; ++k) { woff[k] = s; s += wsum[k]; }
    }
    __syncthreads();
    int excl = woff[w] + v - d;
    if (i < NV) {
        ptr[i] = excl;
        cursor[i] = excl;
        dinv[i] = rsqrtf((float)d + 2.0f);   // SELF_LOOP_W = 2
        if (i == NV - 1) ptr[NV] = excl + d;
    }
}

// edat[p] = (source row, norm = dinv[row]*dinv[col])
__global__ void fill_kernel(const int* __restrict__ tei, const float* __restrict__ dinv,
                            int* __restrict__ cursor, int2* __restrict__ edat) {
    int e = blockIdx.x * blockDim.x + threadIdx.x;
    if (e < ETR) {
        int row = tei[e];
        int col = tei[ETR + e];
        int p = atomicAdd(&cursor[col], 1);
        edat[p] = make_int2(row, __float_as_int(dinv[row] * dinv[col]));
    }
}

// ---------------- gemm2 wrapper ----------------

__global__ __launch_bounds__(256) void gemm2_kernel(
    const unsigned short* __restrict__ A, const unsigned short* __restrict__ Bt,
    unsigned short* __restrict__ C, int M)
{
    gemm_body<128, 256, false>(A, Bt, C, M, blockIdx.x * 128, 0);
}

// ---------------- gather (bf16 in/out), 8-way edge unroll + NT stores ----------------

template<int F, bool RELU>
__global__ __launch_bounds__(256) void gather_kernel(
    const int* __restrict__ ptr, const int2* __restrict__ edat,
    const float* __restrict__ dinv, const unsigned short* __restrict__ hlin,
    const float* __restrict__ bias, unsigned short* __restrict__ hout)
{
    constexpr int V = F / 64;
    int gid = blockIdx.x * blockDim.x + threadIdx.x;
    int node = gid >> 6, lane = gid & 63;
    if (node >= NV) return;
    float dc = dinv[node];
    int j0 = ptr[node], j1 = ptr[node + 1];
    float acc[V] = {};
    const unsigned short* hb = hlin + lane * V;
    const long long* edl = (const long long*)edat;

    int j = j0;
    for (; j + 7 < j1; j += 8) {
        long long e[8];
        #pragma unroll
        for (int u = 0; u < 8; ++u) e[u] = __builtin_nontemporal_load(edl + j + u);
        if constexpr (V == 4) {
            uint2 q[8];
            #pragma unroll
            for (int u = 0; u < 8; ++u)
                q[u] = *(const uint2*)(hb + (size_t)(int)e[u] * F);
            #pragma unroll
            for (int u = 0; u < 8; ++u) {
                float n = __int_as_float((int)(e[u] >> 32));
                acc[0] += n * blo(q[u].x);
                acc[1] += n * bhi(q[u].x);
                acc[2] += n * blo(q[u].y);
                acc[3] += n * bhi(q[u].y);
            }
        } else {
            unsigned q[8];
            #pragma unroll
            for (int u = 0; u < 8; ++u)
                q[u] = *(const unsigned*)(hb + (size_t)(int)e[u] * F);
            #pragma unroll
            for (int u = 0; u < 8; ++u) {
                float n = __int_as_float((int)(e[u] >> 32));
                acc[0] += n * blo(q[u]);
                acc[1] += n * bhi(q[u]);
            }
        }
    }
    for (; j + 3 < j1; j += 4) {
        long long e[4];
        #pragma unroll
        for (int u = 0; u < 4; ++u) e[u] = __builtin_nontemporal_load(edl + j + u);
        if constexpr (V == 4) {
            uint2 q[4];
            #pragma unroll
            for (int u = 0; u < 4; ++u)
                q[u] = *(const uint2*)(hb + (size_t)(int)e[u] * F);
            #pragma unroll
            for (int u = 0; u < 4; ++u) {
                float n = __int_as_float((int)(e[u] >> 32));
                acc[0] += n * blo(q[u].x);
                acc[1] += n * bhi(q[u].x);
                acc[2] += n * blo(q[u].y);
                acc[3] += n * bhi(q[u].y);
            }
        } else {
            unsigned q[4];
            #pragma unroll
            for (int u = 0; u < 4; ++u)
                q[u] = *(const unsigned*)(hb + (size_t)(int)e[u] * F);
            #pragma unroll
            for (int u = 0; u < 4; ++u) {
                float n = __int_as_float((int)(e[u] >> 32));
                acc[0] += n * blo(q[u]);
                acc[1] += n * bhi(q[u]);
            }
        }
    }
    for (; j < j1; ++j) {
        long long e0 = __builtin_nontemporal_load(edl + j);
        float n0 = __int_as_float((int)(e0 >> 32));
        if constexpr (V == 4) {
            uint2 q0 = *(const uint2*)(hb + (size_t)(int)e0 * F);
            acc[0] += n0 * blo(q0.x);
            acc[1] += n0 * bhi(q0.x);
            acc[2] += n0 * blo(q0.y);
            acc[3] += n0 * bhi(q0.y);
        } else {
            unsigned q0 = *(const unsigned*)(hb + (size_t)(int)e0 * F);
            acc[0] += n0 * blo(q0);
            acc[1] += n0 * bhi(q0);
        }
    }

    const unsigned short* ps = hb + (size_t)node * F;
    float sw = 2.0f * dc * dc;
    if constexpr (V == 4) {
        uint2 qs = *(const uint2*)ps;
        float o0 = acc[0] + sw * blo(qs.x) + bias[lane * 4 + 0];
        float o1 = acc[1] + sw * bhi(qs.x) + bias[lane * 4 + 1];
        float o2 = acc[2] + sw * blo(qs.y) + bias[lane * 4 + 2];
        float o3 = acc[3] + sw * bhi(qs.y) + bias[lane * 4 + 3];
        if (RELU) {
            o0 = fmaxf(o0, 0.f); o1 = fmaxf(o1, 0.f);
            o2 = fmaxf(o2, 0.f); o3 = fmaxf(o3, 0.f);
        }
        union { unsigned short u[4]; unsigned long long ll; } pk;
        pk.u[0] = f2b(o0); pk.u[1] = f2b(o1); pk.u[2] = f2b(o2); pk.u[3] = f2b(o3);
        __builtin_nontemporal_store(pk.ll, (unsigned long long*)(hout + (size_t)node * F + lane * 4));
    } else {
        unsigned qs = *(const unsigned*)ps;
        float o0 = acc[0] + sw * blo(qs) + bias[lane * 2 + 0];
        float o1 = acc[1] + sw * bhi(qs) + bias[lane * 2 + 1];
        if (RELU) { o0 = fmaxf(o0, 0.f); o1 = fmaxf(o1, 0.f); }
        union { unsigned short u[2]; unsigned q; } pk;
        pk.u[0] = f2b(o0); pk.u[1] = f2b(o1);
        __builtin_nontemporal_store(pk.q, (unsigned*)(hout + (size_t)node * F + lane * 2));
    }
}

// ---------------- edge MLP via MFMA ----------------

__global__ __launch_bounds__(256) void edge_mlp_mfma_kernel(
    const int* __restrict__ pos, const int* __restrict__ neg,
    const unsigned short* __restrict__ h2, const unsigned short* __restrict__ Wl1t,
    const float* __restrict__ bl1, const float* __restrict__ Wl2,
    const float* __restrict__ bl2, float* __restrict__ out)
{
    __shared__ unsigned short Es[128][128];
    __shared__ unsigned short Ws[64][128];
    int tid = threadIdx.x;
    int lane = tid & 63, w = tid >> 6;
    int fr = lane & 15, g = lane >> 4;
    int e0 = blockIdx.x * 128;

    #pragma unroll
    for (int k = 0; k < 4; ++k) {
        int chunk = tid + k * 256;
        int row = chunk >> 4, c = chunk & 15;
        *(ushortx8*)&Ws[row][(c ^ (row & 7)) * 8] = *(const ushortx8*)&Wl1t[chunk * 8];
    }

    int et = tid >> 1, hh = tid & 1;
    int eg = e0 + et;
    int a, b;
    if (eg < EPOS) { a = pos[eg]; b = pos[EPOS + eg]; }
    else { int i = eg - EPOS; a = neg[i]; b = neg[EPOS + i]; }
    const unsigned short* pa = h2 + (size_t)a * 128 + hh * 64;
    const unsigned short* pb = h2 + (size_t)b * 128 + hh * 64;
    #pragma unroll
    for (int c8 = 0; c8 < 8; ++c8) {
        ushortx8 va = *(const ushortx8*)&pa[c8 * 8];
        ushortx8 vb = *(const ushortx8*)&pb[c8 * 8];
        ushortx8 vs = bf16add8(va, vb);
        int c = hh * 8 + c8;
        *(ushortx8*)&Es[et][(c ^ (et & 7)) * 8] = vs;
    }
    __syncthreads();

    f32x4 acc[2][4] = {};
    #pragma unroll
    for (int ks = 0; ks < 4; ++ks) {
        int c = ks * 4 + g;
        bf16x8 af[2], bfr[4];
        #pragma unroll
        for (int m = 0; m < 2; ++m) {
            int r = w * 32 + m * 16 + fr;
            af[m] = *(const bf16x8*)&Es[r][(c ^ (r & 7)) * 8];
        }
        #pragma unroll
        for (int n = 0; n < 4; ++n) {
            int r = n * 16 + fr;
            bfr[n] = *(const bf16x8*)&Ws[r][(c ^ (r & 7)) * 8];
        }
        #pragma unroll
        for (int m = 0; m < 2; ++m)
            #pragma unroll
            for (int n = 0; n < 4; ++n)
                acc[m][n] = __builtin_amdgcn_mfma_f32_16x16x32_bf16(af[m], bfr[n], acc[m][n], 0, 0, 0);
    }

    float bl2v = bl2[0];
    float b1v[4], w2v[4];
    #pragma unroll
    for (int n = 0; n < 4; ++n) {
        b1v[n] = bl1[n * 16 + fr];
        w2v[n] = Wl2[n * 16 + fr];
    }
    #pragma unroll
    for (int m = 0; m < 2; ++m) {
        float p[4];
        #pragma unroll
        for (int j = 0; j < 4; ++j) {
            float s = 0.f;
            #pragma unroll
            for (int n = 0; n < 4; ++n)
                s += fmaxf(acc[m][n][j] + b1v[n], 0.0f) * w2v[n];
            p[j] = s;
        }
        #pragma unroll
        for (int off = 1; off < 16; off <<= 1) {
            #pragma unroll
            for (int j = 0; j < 4; ++j)
                p[j] += __shfl_xor(p[j], off);
        }
        int ebase = e0 + w * 32 + m * 16 + g * 4;
        #pragma unroll
        for (int j = 0; j < 4; ++j)
            if (fr == j)
                out[ebase + j] = 1.0f / (1.0f + expf(-(p[j] + bl2v)));
    }
}

// ---------------- launch ----------------

extern "C" void kernel_launch(void* const* d_in, const int* in_sizes, int n_in,
                              void* d_out, int out_size, void* d_ws, size_t ws_size,
                              hipStream_t stream) {
    const float* x   = (const float*)d_in[0];
    const int*   tei = (const int*)d_in[1];
    const int*   pos = (const int*)d_in[2];
    const int*   neg = (const int*)d_in[3];
    const float* W1  = (const float*)d_in[4];
    const float* b1  = (const float*)d_in[5];
    const float* W2  = (const float*)d_in[6];
    const float* b2  = (const float*)d_in[7];
    const float* Wl1 = (const float*)d_in[8];
    const float* bl1 = (const float*)d_in[9];
    const float* Wl2 = (const float*)d_in[10];
    const float* bl2 = (const float*)d_in[11];
    float* out = (float*)d_out;

    // workspace (4B-word offsets)
    float* fws = (float*)d_ws;
    int*   iws = (int*)d_ws;
    unsigned short* usws = (unsigned short*)d_ws;
    float* dinv     = fws;                         // [50000]
    int*   deg      = iws + 50000;                 // [50000]
    int*   ptr      = iws + 100000;                // [50001]
    int*   cursor   = iws + 150002;                // [50000]
    int2*  edat     = (int2*)(iws + 200064);       // [800000] int2 -> ends 1800064
    int*   partials = iws + 1800064;               // [64]
    unsigned short* w1t  = usws + 2ull * 1800192;  // [256*256]
    unsigned short* w2t  = usws + 2ull * 1832960;  // [128*256]
    unsigned short* wl1t = usws + 2ull * 1849344;  // [64*128]
    unsigned short* bufX = usws + 2ull * 1853504;  // h2lin bf16
    unsigned short* bufL16 = usws + 2ull * 8253504;  // h1lin bf16, then h2 bf16
    unsigned short* bufH = usws + 2ull * 14653504;   // h1 bf16

    hipMemsetAsync(deg, 0, NV * sizeof(int), stream);

    // fat0: deg histogram + cvt(W1)
    fat0_kernel<<<3381, 256, 0, stream>>>(tei, deg, W1, w1t);

    // fat1: gemm1 (h1lin = bf16(x) @ w1t) + partial sums + cvt(W2, Wl1)
    fat1_kernel<<<991, 256, 0, stream>>>(x, w1t, bufL16, deg, partials, W2, w2t, Wl1, wl1t);

    ptr_kernel<<<49, 1024, 0, stream>>>(deg, partials, ptr, cursor, dinv);
    fill_kernel<<<(ETR + 255) / 256, 256, 0, stream>>>(tei, dinv, cursor, edat);

    // layer 1 gather
    gather_kernel<256, true><<<(NV * 64) / 256, 256, 0, stream>>>(ptr, edat, dinv, bufL16, b1, bufH);

    // layer 2: h2lin = h1 @ w2t -> bufX; gather -> h2 (bufL16)
    gemm2_kernel<<<391, 256, 0, stream>>>(bufH, w2t, bufX, NV);
    gather_kernel<128, false><<<(NV * 64) / 256, 256, 0, stream>>>(ptr, edat, dinv, bufX, b2, bufL16);

    // edge MLP head (MFMA)
    edge_mlp_mfma_kernel<<<ETEST / 128, 256, 0, stream>>>(pos, neg, bufL16, wl1t, bl1, Wl2, bl2, out);
}